// Round 2
// baseline (335.517 us; speedup 1.0000x reference)
//
#include <hip/hip_runtime.h>

#define BB 8192
#define LL 40
#define VV 100000
#define NEG_INF_F (-4294967295.0f)
#define XS 136    // sX row stride (bf16): 128 + 8 pad
#define HS 104    // sH1 row stride (bf16), K padded 80->96
#define XGS 480   // global info_all row stride (bf16), K padded 456->480

typedef __attribute__((ext_vector_type(8))) short short8;
typedef __attribute__((ext_vector_type(4))) float f32x4;

// gfx950 HW bf16 convert: 2 f32 -> packed 2x bf16 (RNE), 1 VALU op.
__device__ __forceinline__ unsigned cvt_pk_bf16(float a, float b) {
  unsigned r;
  asm("v_cvt_pk_bf16_f32 %0, %1, %2" : "=v"(r) : "v"(a), "v"(b));
  return r;
}
__device__ __forceinline__ unsigned short f2bf(float f) {
  return (unsigned short)cvt_pk_bf16(f, f);
}
__device__ __forceinline__ float bf2f(unsigned short s) {
  return __uint_as_float(((unsigned)s) << 16);
}
// sigmoid with v_rcp (1 ulp) instead of the ~10-op exact divide sequence
__device__ __forceinline__ float sigm(float z) {
  return __builtin_amdgcn_rcpf(1.f + __expf(-z));
}

// B' = bf16( Wsd + q * Wd )
__device__ __forceinline__ short8 fuseB(short8 wsd, short8 wd, float4 qa, float4 qb) {
  float qv[8] = {qa.x, qa.y, qa.z, qa.w, qb.x, qb.y, qb.z, qb.w};
  float f[8];
#pragma unroll
  for (int j = 0; j < 8; j++)
    f[j] = bf2f((unsigned short)wsd[j]) + qv[j] * bf2f((unsigned short)wd[j]);
  uint4 o;
  o.x = cvt_pk_bf16(f[0], f[1]);
  o.y = cvt_pk_bf16(f[2], f[3]);
  o.z = cvt_pk_bf16(f[4], f[5]);
  o.w = cvt_pk_bf16(f[6], f[7]);
  return __builtin_bit_cast(short8, o);
}

// ---------------- prep (fused, parallel; blocks >=306 convert embQ f32->bf16) ----------------
__global__ void prep_all(const float* __restrict__ W1, float* __restrict__ wqcT,
                         unsigned short* __restrict__ WsdpT,
                         const float* __restrict__ aW2, unsigned short* __restrict__ W2bT,
                         const float* __restrict__ fW2, unsigned short* __restrict__ W2fT,
                         const float* __restrict__ fW1, const float* __restrict__ g,
                         const float* __restrict__ vr, unsigned short* __restrict__ W1fT,
                         const float* __restrict__ fb1, const float* __restrict__ be,
                         const float* __restrict__ mn, float* __restrict__ b1p,
                         const float* __restrict__ embQ, unsigned short* __restrict__ embQb) {
  __shared__ float red[4];
  int bid = blockIdx.x, t = threadIdx.x;
  if (bid < 40) {
    int i = bid * 256 + t;           // exactly 10240
    int h = i >> 7, k = i & 127;
    float a = W1[k * 80 + h];
    float b = W1[(128 + k) * 80 + h];
    float c = W1[(256 + k) * 80 + h];
    float d = W1[(384 + k) * 80 + h];
    wqcT[h * 132 + k] = a + c;
    WsdpT[h * 256 + k] = f2bf(b - c);
    WsdpT[h * 256 + 128 + k] = f2bf(d);
  } else if (bid < 58) {
    int i = (bid - 40) * 256 + t;    // exactly 4608
    int n = i / 96, k = i % 96;
    W2bT[i] = (n < 40 && k < 80) ? f2bf(aW2[k * 40 + n]) : (unsigned short)0;
  } else if (bid < 76) {
    int i = (bid - 58) * 256 + t;
    int n = i / 96, k = i % 96;
    W2fT[i] = (n < 40 && k < 80) ? f2bf(fW2[k * 40 + n]) : (unsigned short)0;
  } else if (bid < 226) {
    int i = (bid - 76) * 256 + t;    // exactly 38400
    int n = i / 480, k = i % 480;
    float v = 0.f;
    if (k < 456) v = fW1[k * 80 + n] * g[k] * rsqrtf(vr[k] + 1e-3f);
    W1fT[i] = f2bf(v);
  } else if (bid < 306) {
    int n = bid - 226;               // 0..79
    float p = 0.f;
    for (int k = t; k < 456; k += 256) {
      float sc = g[k] * rsqrtf(vr[k] + 1e-3f);
      p += (be[k] - mn[k] * sc) * fW1[k * 80 + n];
    }
    for (int off = 32; off; off >>= 1) p += __shfl_xor(p, off, 64);
    if ((t & 63) == 0) red[t >> 6] = p;
    __syncthreads();
    if (t == 0) b1p[n] = fb1[n] + red[0] + red[1] + red[2] + red[3];
  } else {
    // embQ (2*100000*64 f32 = 12.8M) -> bf16, grid-stride over float4 units
    const float4* src = (const float4*)embQ;
    uint2* dst = (uint2*)embQb;
    for (int i = (bid - 306) * 256 + t; i < 3200000; i += 2048 * 256) {
      float4 v = src[i];
      uint2 p;
      p.x = cvt_pk_bf16(v.x, v.y);
      p.y = cvt_pk_bf16(v.z, v.w);
      dst[i] = p;
    }
  }
}

// ---------------- kernel A: attention + pool, one row per block ----------------
// Gather-BW bound: seq gathers read the bf16 table copy (half the random bytes).
// Gathers are issued into registers, q-compute overlaps their latency, then they
// land in sX before barrier-2. Softmax is per-wave (waves 0,1), no 3rd barrier.

__launch_bounds__(256, 8)
__global__ void din_att(const float* __restrict__ dense, const int* __restrict__ sparsei,
                        const int* __restrict__ seqi, const int* __restrict__ itemi,
                        const float* __restrict__ embS, const float* __restrict__ embQ,
                        const unsigned short* __restrict__ embQb,
                        const float* __restrict__ wqcT, const unsigned short* __restrict__ WsdpT,
                        const unsigned short* __restrict__ W2bT,
                        const float* __restrict__ ab1, const float* __restrict__ ab2,
                        const float* __restrict__ aWf, const float* __restrict__ abf,
                        unsigned short* __restrict__ Xg) {
  __shared__ __align__(16) char smem[20352];
  unsigned short* sX  = (unsigned short*)smem;             // 40 x 136 bf16
  unsigned short* sH1 = (unsigned short*)(smem + 10880);   // 40 x 104 bf16
  float* sQ    = (float*)(smem + 19200);                   // 128
  float* sQCp  = sQ + 128;                                 // 80 (qconst; later 2x40 att)
  float* sLA   = sQCp + 80;                                // 40 (logit accum)
  float* sMask = sLA + 40;                                 // 40

  const int t = threadIdx.x;        // 0..255
  const int b = blockIdx.x;
  const int wv = t >> 6, ln = t & 63, m16 = ln & 15, quad = ln >> 4;
  unsigned short* xrow = Xg + (size_t)b * XGS;

  // ---- phase 0: item gather -> sQ (+ Xg item cols) + zero inits ----
  if (t < 32) {
    int f = t >> 4, sub = t & 15;
    int idx = itemi[b * 2 + f];
    float4 v = *(const float4*)(embQ + ((size_t)(f * VV + idx)) * 64 + sub * 4);
    *(float4*)(sQ + f * 64 + sub * 4) = v;
    uint2 p;
    p.x = cvt_pk_bf16(v.x, v.y);
    p.y = cvt_pk_bf16(v.z, v.w);
    *(uint2*)(xrow + 128 + f * 64 + sub * 4) = p;          // item cols 128..255
  } else if (t >= 100 && t < 140) {
    sLA[t - 100] = 0.f;
  }
  for (int i = t; i < 320; i += 256) {   // sH1 K-pad cols 80..95, rows 0..39 (NaN guard)
    int r = i >> 3, c = i & 7;
    ((unsigned*)sH1)[r * 52 + 40 + c] = 0u;
  }
  __syncthreads();

  // ---- phase 2: issue seq gathers -> regs; overlap sparse/dense Xg, qconst, B' ----
  uint2 gv[5];
#pragma unroll
  for (int it = 0; it < 5; it++) {
    int i = t + (it << 8);
    int r = i >> 4, sub = i & 15, f = r & 1;
    int idx = seqi[b * 80 + r];
    if (embQb) {
      gv[it] = *(const uint2*)(embQb + ((size_t)(f * VV + idx)) * 64 + sub * 4);
    } else {
      float4 v = *(const float4*)(embQ + ((size_t)(f * VV + idx)) * 64 + sub * 4);
      gv[it].x = cvt_pk_bf16(v.x, v.y);
      gv[it].y = cvt_pk_bf16(v.z, v.w);
    }
  }
  if (t >= 32 && t < 80) {
    int j = t - 32, f = j >> 4, sub = j & 15;
    int idx = sparsei[b * 3 + f];
    float4 v = *(const float4*)(embS + ((size_t)(f * VV + idx)) * 64 + sub * 4);
    uint2 p;
    p.x = cvt_pk_bf16(v.x, v.y);
    p.y = cvt_pk_bf16(v.z, v.w);
    *(uint2*)(xrow + 264 + f * 64 + sub * 4) = p;          // sparse cols 264..455
  } else if (t >= 80 && t < 88) {
    xrow[256 + (t - 80)] = f2bf(dense[b * 8 + (t - 80)]);  // dense cols 256..263
  } else if (t >= 88 && t < 100) {
    ((unsigned*)xrow)[228 + (t - 88)] = 0u;                // K-pad cols 456..479
  }
  if (t < 80) {   // qconst, K=128, 2 accumulators (gathers in flight above)
    float acc0 = ab1[t], acc1 = 0.f;
    const float* wq = wqcT + t * 132;
    for (int k = 0; k < 128; k += 8) {
      float4 w0 = *(const float4*)(wq + k);
      float4 w1 = *(const float4*)(wq + k + 4);
      float4 q0 = *(const float4*)(sQ + k);
      float4 q1 = *(const float4*)(sQ + k + 4);
      acc0 += q0.x * w0.x + q0.y * w0.y + q0.z * w0.z + q0.w * w0.w;
      acc1 += q1.x * w1.x + q1.y * w1.y + q1.z * w1.z + q1.w * w1.w;
    }
    sQCp[t] = acc0 + acc1;
  }
  short8 Bp[4];
  {
    const unsigned short* br = WsdpT + (size_t)(wv * 16 + m16) * 256 + quad * 8;
#pragma unroll
    for (int kt = 0; kt < 4; kt++) {
      short8 w1 = *(const short8*)(br + kt * 32);
      short8 w2 = *(const short8*)(br + 128 + kt * 32);
      int k0 = quad * 8 + kt * 32;
      Bp[kt] = fuseB(w1, w2, *(const float4*)(sQ + k0), *(const float4*)(sQ + k0 + 4));
    }
  }
  // land gathers into sX + mask
#pragma unroll
  for (int it = 0; it < 5; it++) {
    int i = t + (it << 8);
    int r = i >> 4, sub = i & 15, l = r >> 1, f = r & 1;
    *(uint2*)(sX + l * XS + f * 64 + sub * 4) = gv[it];
  }
  if ((t & 31) == 0) {   // threads 0,32,..: r even & sub==0 for all 5 its (L1-hot reload)
#pragma unroll
    for (int it = 0; it < 5; it++) {
      int r = (t >> 4) + (it << 4);
      sMask[r >> 1] = (seqi[b * 80 + r] != 0) ? 0.f : NEG_INF_F;
    }
  }
  __syncthreads();

  // ---- phase 3: layer1 MFMA, K=128, wave = N-tile; waves 0-2 inline nt=4 ----
  {
    const int h = wv * 16 + m16;
    const float qc = sQCp[h];
#pragma unroll
    for (int mt = 0; mt < 3; mt++) {
      f32x4 acc = {0.f, 0.f, 0.f, 0.f};
      const unsigned short* ar = sX + (mt * 16 + m16) * XS + quad * 8;
#pragma unroll
      for (int kt = 0; kt < 4; kt++) {
        short8 a = *(const short8*)(ar + kt * 32);
        acc = __builtin_amdgcn_mfma_f32_16x16x32_bf16(a, Bp[kt], acc, 0, 0, 0);
      }
      float s0 = sigm(acc[0] + qc), s1 = sigm(acc[1] + qc);
      float s2 = sigm(acc[2] + qc), s3 = sigm(acc[3] + qc);
      unsigned p01 = cvt_pk_bf16(s0, s1), p23 = cvt_pk_bf16(s2, s3);
      int l0 = mt * 16 + quad * 4;           // either all 4 rows valid or none
      if (l0 < 40) {
        sH1[(l0 + 0) * HS + h] = (unsigned short)p01;
        sH1[(l0 + 1) * HS + h] = (unsigned short)(p01 >> 16);
        sH1[(l0 + 2) * HS + h] = (unsigned short)p23;
        sH1[(l0 + 3) * HS + h] = (unsigned short)(p23 >> 16);
      }
    }
    if (wv < 3) {   // nt = 4, mt = wv : load+fuse+mfma inline, no persistent frags
      const unsigned short* br = WsdpT + (size_t)(64 + m16) * 256 + quad * 8;
      const unsigned short* ar = sX + (wv * 16 + m16) * XS + quad * 8;
      f32x4 acc = {0.f, 0.f, 0.f, 0.f};
#pragma unroll
      for (int kt = 0; kt < 4; kt++) {
        short8 w1 = *(const short8*)(br + kt * 32);
        short8 w2 = *(const short8*)(br + 128 + kt * 32);
        int k0 = quad * 8 + kt * 32;
        short8 bp = fuseB(w1, w2, *(const float4*)(sQ + k0), *(const float4*)(sQ + k0 + 4));
        short8 a = *(const short8*)(ar + kt * 32);
        acc = __builtin_amdgcn_mfma_f32_16x16x32_bf16(a, bp, acc, 0, 0, 0);
      }
      int h4 = 64 + m16;
      float qc4 = sQCp[h4];
      float s0 = sigm(acc[0] + qc4), s1 = sigm(acc[1] + qc4);
      float s2 = sigm(acc[2] + qc4), s3 = sigm(acc[3] + qc4);
      unsigned p01 = cvt_pk_bf16(s0, s1), p23 = cvt_pk_bf16(s2, s3);
      int l0 = wv * 16 + quad * 4;
      if (l0 < 40) {
        sH1[(l0 + 0) * HS + h4] = (unsigned short)p01;
        sH1[(l0 + 1) * HS + h4] = (unsigned short)(p01 >> 16);
        sH1[(l0 + 2) * HS + h4] = (unsigned short)p23;
        sH1[(l0 + 3) * HS + h4] = (unsigned short)(p23 >> 16);
      }
    }
  }
  __syncthreads();

  // ---- phase 4: layer2 MFMA + fused logit reduction into sLA ----
  for (int tile = wv; tile < 9; tile += 4) {
    int mt = tile / 3, nt = tile % 3;
    f32x4 acc = {0.f, 0.f, 0.f, 0.f};
    int arow = mt * 16 + m16;
    if (arow > 39) arow = 39;   // keep garbage A-rows inside the LDS block (gated below)
    const unsigned short* ar = sH1 + arow * HS + quad * 8;
    const unsigned short* br = W2bT + (nt * 16 + m16) * 96 + quad * 8;
#pragma unroll
    for (int kt = 0; kt < 3; kt++) {
      short8 a = *(const short8*)(ar + kt * 32);
      short8 bb = *(const short8*)(br + kt * 32);
      acc = __builtin_amdgcn_mfma_f32_16x16x32_bf16(a, bb, acc, 0, 0, 0);
    }
    int j = nt * 16 + m16;
    float b2 = (j < 40) ? ab2[j] : 0.f;
    float wf = (j < 40) ? aWf[j] : 0.f;
    float c[4];
#pragma unroll
    for (int r = 0; r < 4; r++) {
      float h2 = sigm(acc[r] + b2);
      c[r] = (j < 40) ? h2 * wf : 0.f;    // gate garbage j-lanes (NaN-safe select)
    }
#pragma unroll
    for (int off = 1; off < 16; off <<= 1) {
#pragma unroll
      for (int r = 0; r < 4; r++) c[r] += __shfl_xor(c[r], off, 64);
    }
    if (m16 == 0) {
#pragma unroll
      for (int r = 0; r < 4; r++) {
        int l = mt * 16 + quad * 4 + r;
        if (l < 40) atomicAdd(&sLA[l], c[r]);
      }
    }
  }
  __syncthreads();

  // ---- phase 5+6: per-wave softmax + pool (waves 0,1; wave-local, no barrier) ----
  if (wv < 2) {
    float logit = -3.0e38f;
    if (ln < 40) logit = sLA[ln] + abf[0] + sMask[ln];
    float mx = logit;
    for (int off = 32; off; off >>= 1) mx = fmaxf(mx, __shfl_xor(mx, off, 64));
    float ex = (ln < 40) ? __expf(logit - mx) : 0.f;
    float sm = ex;
    for (int off = 32; off; off >>= 1) sm += __shfl_xor(sm, off, 64);
    float* av = sQCp + wv * 40;          // qconst space is dead now; per-wave att copy
    if (ln < 40) av[ln] = ex * __builtin_amdgcn_rcpf(sm);
    float acc = 0.f;
    for (int l = 0; l < 40; l++) acc += av[l] * bf2f(sX[l * XS + t]);
    xrow[t] = f2bf(acc);                 // pool cols 0..127
  }
  // waves 2,3 retire here
}

// ---------------- kernel B: batched FFN GEMM, 16 rows per block ----------------

__launch_bounds__(256, 2)
__global__ void din_ffn(const unsigned short* __restrict__ Xg,
                        const unsigned short* __restrict__ W1fT, const float* __restrict__ b1p,
                        const float* __restrict__ fa1,
                        const unsigned short* __restrict__ W2fT, const float* __restrict__ fb2,
                        const float* __restrict__ fa2,
                        const float* __restrict__ oW, const float* __restrict__ ob,
                        float* __restrict__ out) {
  __shared__ __align__(16) unsigned short sXB[16 * 488];
  __shared__ __align__(16) unsigned short sH1B[16 * HS];
  __shared__ float sH2B[16 * 41];
  const int t = threadIdx.x, blk = blockIdx.x;
  const int wv = t >> 6, ln = t & 63, m16 = ln & 15, quad = ln >> 4;

  // prefetch GEMM1 B-fragments for nt = wv (15 frags, K=480)
  short8 Bf[15];
  {
    const unsigned short* br = W1fT + (size_t)(wv * 16 + m16) * 480 + quad * 8;
#pragma unroll
    for (int kt = 0; kt < 15; kt++) Bf[kt] = *(const short8*)(br + kt * 32);
  }

  // stage X tile (16 rows x 480 bf16) + zero H1 K-pad
  for (int i = t; i < 960; i += 256) {
    int r = i / 60, c = i % 60;
    *(uint4*)(sXB + r * 488 + c * 8) =
        *(const uint4*)(Xg + (size_t)(blk * 16 + r) * XGS + c * 8);
  }
  if (t < 128) {
    int r = t >> 3, c = t & 7;
    ((unsigned*)sH1B)[r * 52 + 40 + c] = 0u;
  }
  __syncthreads();

  // GEMM1: [16x480] @ [480x80]; wave = N-tile; wave 0 also does nt=4
  {
    int h = wv * 16 + m16;
    f32x4 acc = {0.f, 0.f, 0.f, 0.f};
    const unsigned short* ar = sXB + m16 * 488 + quad * 8;
#pragma unroll
    for (int kt = 0; kt < 15; kt++) {
      short8 a = *(const short8*)(ar + kt * 32);
      acc = __builtin_amdgcn_mfma_f32_16x16x32_bf16(a, Bf[kt], acc, 0, 0, 0);
    }
    float b1v = b1p[h], a1v = fa1[h];
    float z0 = acc[0] + b1v, z1 = acc[1] + b1v, z2 = acc[2] + b1v, z3 = acc[3] + b1v;
    z0 = z0 > 0.f ? z0 : a1v * z0;
    z1 = z1 > 0.f ? z1 : a1v * z1;
    z2 = z2 > 0.f ? z2 : a1v * z2;
    z3 = z3 > 0.f ? z3 : a1v * z3;
    unsigned p01 = cvt_pk_bf16(z0, z1), p23 = cvt_pk_bf16(z2, z3);
    int l0 = quad * 4;
    sH1B[(l0 + 0) * HS + h] = (unsigned short)p01;
    sH1B[(l0 + 1) * HS + h] = (unsigned short)(p01 >> 16);
    sH1B[(l0 + 2) * HS + h] = (unsigned short)p23;
    sH1B[(l0 + 3) * HS + h] = (unsigned short)(p23 >> 16);
    if (wv == 0) {   // nt = 4
      short8 B4[15];
      const unsigned short* br = W1fT + (size_t)(64 + m16) * 480 + quad * 8;
#pragma unroll
      for (int kt = 0; kt < 15; kt++) B4[kt] = *(const short8*)(br + kt * 32);
      f32x4 acc4 = {0.f, 0.f, 0.f, 0.f};
#pragma unroll
      for (int kt = 0; kt < 15; kt++) {
        short8 a = *(const short8*)(ar + kt * 32);
        acc4 = __builtin_amdgcn_mfma_f32_16x16x32_bf16(a, B4[kt], acc4, 0, 0, 0);
      }
      int h4 = 64 + m16;
      float b1v4 = b1p[h4], a1v4 = fa1[h4];
      float y0 = acc4[0] + b1v4, y1 = acc4[1] + b1v4, y2 = acc4[2] + b1v4, y3 = acc4[3] + b1v4;
      y0 = y0 > 0.f ? y0 : a1v4 * y0;
      y1 = y1 > 0.f ? y1 : a1v4 * y1;
      y2 = y2 > 0.f ? y2 : a1v4 * y2;
      y3 = y3 > 0.f ? y3 : a1v4 * y3;
      unsigned q01 = cvt_pk_bf16(y0, y1), q23 = cvt_pk_bf16(y2, y3);
      sH1B[(l0 + 0) * HS + h4] = (unsigned short)q01;
      sH1B[(l0 + 1) * HS + h4] = (unsigned short)(q01 >> 16);
      sH1B[(l0 + 2) * HS + h4] = (unsigned short)q23;
      sH1B[(l0 + 3) * HS + h4] = (unsigned short)(q23 >> 16);
    }
  }
  __syncthreads();

  // GEMM2: [16x96] @ [96x48], waves 0-2
  if (wv < 3) {
    f32x4 acc = {0.f, 0.f, 0.f, 0.f};
    const unsigned short* ar = sH1B + m16 * HS + quad * 8;
    const unsigned short* br = W2fT + (wv * 16 + m16) * 96 + quad * 8;
#pragma unroll
    for (int kt = 0; kt < 3; kt++) {
      short8 a = *(const short8*)(ar + kt * 32);
      short8 bb = *(const short8*)(br + kt * 32);
      acc = __builtin_amdgcn_mfma_f32_16x16x32_bf16(a, bb, acc, 0, 0, 0);
    }
    int j = wv * 16 + m16;
    if (j < 40) {
      float b2 = fb2[j], a2 = fa2[j];
#pragma unroll
      for (int r = 0; r < 4; r++) {
        int l = quad * 4 + r;
        float z = acc[r] + b2;
        sH2B[l * 41 + j] = z > 0.f ? z : a2 * z;
      }
    }
  }
  __syncthreads();

  // final dot(40) + sigmoid
  if (t < 16) {
    float acc = ob[0];
    for (int j = 0; j < 40; j++) acc += sH2B[t * 41 + j] * oW[j];
    out[blk * 16 + t] = sigm(acc);
  }
}

// ---------------- launch ----------------

extern "C" void kernel_launch(void* const* d_in, const int* in_sizes, int n_in,
                              void* d_out, int out_size, void* d_ws, size_t ws_size,
                              hipStream_t stream) {
  const float* dense  = (const float*)d_in[0];
  const int*   sparsei = (const int*)d_in[1];
  const int*   seqi   = (const int*)d_in[2];
  const int*   itemi  = (const int*)d_in[3];
  const float* embS   = (const float*)d_in[4];
  const float* embQ   = (const float*)d_in[5];
  const float* aW1    = (const float*)d_in[6];
  const float* ab1    = (const float*)d_in[7];
  const float* aW2    = (const float*)d_in[8];
  const float* ab2    = (const float*)d_in[9];
  const float* aWf    = (const float*)d_in[10];
  const float* abf    = (const float*)d_in[11];
  const float* bng    = (const float*)d_in[12];
  const float* bnb    = (const float*)d_in[13];
  const float* bnm    = (const float*)d_in[14];
  const float* bnv    = (const float*)d_in[15];
  const float* fW1    = (const float*)d_in[16];
  const float* fb1    = (const float*)d_in[17];
  const float* fa1    = (const float*)d_in[18];
  const float* fW2    = (const float*)d_in[19];
  const float* fb2    = (const float*)d_in[20];
  const float* fa2    = (const float*)d_in[21];
  const float* oW     = (const float*)d_in[22];
  const float* ob     = (const float*)d_in[23];
  float* out = (float*)d_out;

  float* ws = (float*)d_ws;
  float* wqcT = ws;                                          // 10560 f
  float* b1p  = ws + 10560;                                  // 80 f
  unsigned short* WsdpT = (unsigned short*)(ws + 10640);     // 20480 u16
  unsigned short* W2bT  = (unsigned short*)(ws + 20880);     // 4608 u16
  unsigned short* W2fT  = (unsigned short*)(ws + 23184);     // 4608 u16
  unsigned short* W1fT  = (unsigned short*)(ws + 25488);     // 38400 u16
  unsigned short* Xg    = (unsigned short*)(ws + 44688);     // 8192*480 u16 = 7864320 B

  // bf16 copy of embQ (12.8M bf16 = 25.6 MB) after Xg, if workspace allows
  size_t base = 44688ull * 4 + 8192ull * 480 * 2;            // 8,043,072 B (8B aligned)
  size_t need = base + 12800000ull * 2;
  unsigned short* embQb = (ws_size >= need)
      ? (unsigned short*)((char*)d_ws + base) : (unsigned short*)0;

  int prep_grid = embQb ? 2354 : 306;
  prep_all<<<prep_grid, 256, 0, stream>>>(aW1, wqcT, WsdpT, aW2, W2bT, fW2, W2fT,
                                          fW1, bng, bnv, W1fT, fb1, bnb, bnm, b1p,
                                          embQ, embQb);
  din_att<<<BB, 256, 0, stream>>>(dense, sparsei, seqi, itemi, embS, embQ, embQb,
                                  wqcT, WsdpT, W2bT, ab1, ab2, aWf, abf, Xg);
  din_ffn<<<512, 256, 0, stream>>>(Xg, W1fT, b1p, fa1, W2fT, fb2, fa2, oW, ob, out);
}

// Round 6
// 329.233 us; speedup vs baseline: 1.0191x; 1.0191x over previous
//
#include <hip/hip_runtime.h>

#define BB 8192
#define LL 40
#define VV 100000
#define NEG_INF_F (-4294967295.0f)
#define XS 136    // sX row stride (bf16): 128 + 8 pad
#define HS 104    // sH1 row stride (bf16), K padded 80->96
#define XGS 480   // global info_all row stride (bf16), K padded 456->480

typedef __attribute__((ext_vector_type(8))) short short8;
typedef __attribute__((ext_vector_type(4))) float f32x4;

// gfx950 HW bf16 convert: 2 f32 -> packed 2x bf16 (RNE), 1 VALU op.
__device__ __forceinline__ unsigned cvt_pk_bf16(float a, float b) {
  unsigned r;
  asm("v_cvt_pk_bf16_f32 %0, %1, %2" : "=v"(r) : "v"(a), "v"(b));
  return r;
}
__device__ __forceinline__ unsigned short f2bf(float f) {
  return (unsigned short)cvt_pk_bf16(f, f);
}
__device__ __forceinline__ float bf2f(unsigned short s) {
  return __uint_as_float(((unsigned)s) << 16);
}
// sigmoid with v_rcp (1 ulp) instead of the ~10-op exact divide sequence
__device__ __forceinline__ float sigm(float z) {
  return __builtin_amdgcn_rcpf(1.f + __expf(-z));
}

// B' = bf16( Wsd + q * Wd )
__device__ __forceinline__ short8 fuseB(short8 wsd, short8 wd, float4 qa, float4 qb) {
  float qv[8] = {qa.x, qa.y, qa.z, qa.w, qb.x, qb.y, qb.z, qb.w};
  float f[8];
#pragma unroll
  for (int j = 0; j < 8; j++)
    f[j] = bf2f((unsigned short)wsd[j]) + qv[j] * bf2f((unsigned short)wd[j]);
  uint4 o;
  o.x = cvt_pk_bf16(f[0], f[1]);
  o.y = cvt_pk_bf16(f[2], f[3]);
  o.z = cvt_pk_bf16(f[4], f[5]);
  o.w = cvt_pk_bf16(f[6], f[7]);
  return __builtin_bit_cast(short8, o);
}

// ---------------- prep (fused, parallel; blocks >=306 convert embQ f32->bf16) ----------------
__global__ void prep_all(const float* __restrict__ W1, float* __restrict__ wqcT,
                         unsigned short* __restrict__ WsdpT,
                         const float* __restrict__ aW2, unsigned short* __restrict__ W2bT,
                         const float* __restrict__ fW2, unsigned short* __restrict__ W2fT,
                         const float* __restrict__ fW1, const float* __restrict__ g,
                         const float* __restrict__ vr, unsigned short* __restrict__ W1fT,
                         const float* __restrict__ fb1, const float* __restrict__ be,
                         const float* __restrict__ mn, float* __restrict__ b1p,
                         const float* __restrict__ embQ, unsigned short* __restrict__ embQb) {
  __shared__ float red[4];
  int bid = blockIdx.x, t = threadIdx.x;
  if (bid < 40) {
    int i = bid * 256 + t;           // exactly 10240
    int h = i >> 7, k = i & 127;
    float a = W1[k * 80 + h];
    float b = W1[(128 + k) * 80 + h];
    float c = W1[(256 + k) * 80 + h];
    float d = W1[(384 + k) * 80 + h];
    wqcT[h * 132 + k] = a + c;
    WsdpT[h * 256 + k] = f2bf(b - c);
    WsdpT[h * 256 + 128 + k] = f2bf(d);
  } else if (bid < 58) {
    int i = (bid - 40) * 256 + t;    // exactly 4608
    int n = i / 96, k = i % 96;
    W2bT[i] = (n < 40 && k < 80) ? f2bf(aW2[k * 40 + n]) : (unsigned short)0;
  } else if (bid < 76) {
    int i = (bid - 58) * 256 + t;
    int n = i / 96, k = i % 96;
    W2fT[i] = (n < 40 && k < 80) ? f2bf(fW2[k * 40 + n]) : (unsigned short)0;
  } else if (bid < 226) {
    int i = (bid - 76) * 256 + t;    // exactly 38400
    int n = i / 480, k = i % 480;
    float v = 0.f;
    if (k < 456) v = fW1[k * 80 + n] * g[k] * rsqrtf(vr[k] + 1e-3f);
    W1fT[i] = f2bf(v);
  } else if (bid < 306) {
    int n = bid - 226;               // 0..79
    float p = 0.f;
    for (int k = t; k < 456; k += 256) {
      float sc = g[k] * rsqrtf(vr[k] + 1e-3f);
      p += (be[k] - mn[k] * sc) * fW1[k * 80 + n];
    }
    for (int off = 32; off; off >>= 1) p += __shfl_xor(p, off, 64);
    if ((t & 63) == 0) red[t >> 6] = p;
    __syncthreads();
    if (t == 0) b1p[n] = fb1[n] + red[0] + red[1] + red[2] + red[3];
  } else {
    // embQ (2*100000*64 f32 = 12.8M) -> bf16, grid-stride over float4 units
    const float4* src = (const float4*)embQ;
    uint2* dst = (uint2*)embQb;
    for (int i = (bid - 306) * 256 + t; i < 3200000; i += 2048 * 256) {
      float4 v = src[i];
      uint2 p;
      p.x = cvt_pk_bf16(v.x, v.y);
      p.y = cvt_pk_bf16(v.z, v.w);
      dst[i] = p;
    }
  }
}

// ---------------- kernel A: attention + pool, one row per block ----------------
// Round-2 verified body; ONE change: seq gather is 640 x uint4 (16 B, 8 threads
// per 64-elem half-row) instead of 1280 x uint2 -- halves gather request count.
// Probes whether din_att is bound by outstanding-load slots vs a per-WG floor.

__launch_bounds__(256, 8)
__global__ void din_att(const float* __restrict__ dense, const int* __restrict__ sparsei,
                        const int* __restrict__ seqi, const int* __restrict__ itemi,
                        const float* __restrict__ embS, const float* __restrict__ embQ,
                        const unsigned short* __restrict__ embQb,
                        const float* __restrict__ wqcT, const unsigned short* __restrict__ WsdpT,
                        const unsigned short* __restrict__ W2bT,
                        const float* __restrict__ ab1, const float* __restrict__ ab2,
                        const float* __restrict__ aWf, const float* __restrict__ abf,
                        unsigned short* __restrict__ Xg) {
  __shared__ __align__(16) char smem[20352];
  unsigned short* sX  = (unsigned short*)smem;             // 40 x 136 bf16
  unsigned short* sH1 = (unsigned short*)(smem + 10880);   // 40 x 104 bf16
  float* sQ    = (float*)(smem + 19200);                   // 128
  float* sQCp  = sQ + 128;                                 // 80 (qconst; later 2x40 att)
  float* sLA   = sQCp + 80;                                // 40 (logit accum)
  float* sMask = sLA + 40;                                 // 40

  const int t = threadIdx.x;        // 0..255
  const int b = blockIdx.x;
  const int wv = t >> 6, ln = t & 63, m16 = ln & 15, quad = ln >> 4;
  unsigned short* xrow = Xg + (size_t)b * XGS;

  // ---- phase 0: item gather -> sQ (+ Xg item cols) + zero inits ----
  if (t < 32) {
    int f = t >> 4, sub = t & 15;
    int idx = itemi[b * 2 + f];
    float4 v = *(const float4*)(embQ + ((size_t)(f * VV + idx)) * 64 + sub * 4);
    *(float4*)(sQ + f * 64 + sub * 4) = v;
    uint2 p;
    p.x = cvt_pk_bf16(v.x, v.y);
    p.y = cvt_pk_bf16(v.z, v.w);
    *(uint2*)(xrow + 128 + f * 64 + sub * 4) = p;          // item cols 128..255
  } else if (t >= 100 && t < 140) {
    sLA[t - 100] = 0.f;
  }
  for (int i = t; i < 320; i += 256) {   // sH1 K-pad cols 80..95, rows 0..39 (NaN guard)
    int r = i >> 3, c = i & 7;
    ((unsigned*)sH1)[r * 52 + 40 + c] = 0u;
  }
  __syncthreads();

  // ---- phase 2: issue seq gathers (640 x uint4); overlap sparse/dense Xg, qconst, B' ----
  uint4 g0, g1, g2;
  const bool has3 = (t < 128);
  {
    int i0 = t, i1 = t + 256, i2 = t + 512;
    int r0 = i0 >> 3, r1 = i1 >> 3, r2 = i2 >> 3;   // 8 threads per (l,f) half-row
    if (embQb) {
      g0 = *(const uint4*)(embQb + ((size_t)((r0 & 1) * VV + seqi[b * 80 + r0])) * 64 + (i0 & 7) * 8);
      g1 = *(const uint4*)(embQb + ((size_t)((r1 & 1) * VV + seqi[b * 80 + r1])) * 64 + (i1 & 7) * 8);
      if (has3)
        g2 = *(const uint4*)(embQb + ((size_t)((r2 & 1) * VV + seqi[b * 80 + r2])) * 64 + (i2 & 7) * 8);
    } else {
      // fallback: f32 table, two float4 per unit, convert to the same packing
      const float* p0 = embQ + ((size_t)((r0 & 1) * VV + seqi[b * 80 + r0])) * 64 + (i0 & 7) * 8;
      const float* p1 = embQ + ((size_t)((r1 & 1) * VV + seqi[b * 80 + r1])) * 64 + (i1 & 7) * 8;
      float4 a0 = *(const float4*)p0, a1 = *(const float4*)(p0 + 4);
      float4 b0 = *(const float4*)p1, b1 = *(const float4*)(p1 + 4);
      g0.x = cvt_pk_bf16(a0.x, a0.y); g0.y = cvt_pk_bf16(a0.z, a0.w);
      g0.z = cvt_pk_bf16(a1.x, a1.y); g0.w = cvt_pk_bf16(a1.z, a1.w);
      g1.x = cvt_pk_bf16(b0.x, b0.y); g1.y = cvt_pk_bf16(b0.z, b0.w);
      g1.z = cvt_pk_bf16(b1.x, b1.y); g1.w = cvt_pk_bf16(b1.z, b1.w);
      if (has3) {
        const float* p2 = embQ + ((size_t)((r2 & 1) * VV + seqi[b * 80 + r2])) * 64 + (i2 & 7) * 8;
        float4 c0 = *(const float4*)p2, c1 = *(const float4*)(p2 + 4);
        g2.x = cvt_pk_bf16(c0.x, c0.y); g2.y = cvt_pk_bf16(c0.z, c0.w);
        g2.z = cvt_pk_bf16(c1.x, c1.y); g2.w = cvt_pk_bf16(c1.z, c1.w);
      }
    }
  }
  if (t >= 32 && t < 80) {
    int j = t - 32, f = j >> 4, sub = j & 15;
    int idx = sparsei[b * 3 + f];
    float4 v = *(const float4*)(embS + ((size_t)(f * VV + idx)) * 64 + sub * 4);
    uint2 p;
    p.x = cvt_pk_bf16(v.x, v.y);
    p.y = cvt_pk_bf16(v.z, v.w);
    *(uint2*)(xrow + 264 + f * 64 + sub * 4) = p;          // sparse cols 264..455
  } else if (t >= 80 && t < 88) {
    xrow[256 + (t - 80)] = f2bf(dense[b * 8 + (t - 80)]);  // dense cols 256..263
  } else if (t >= 88 && t < 100) {
    ((unsigned*)xrow)[228 + (t - 88)] = 0u;                // K-pad cols 456..479
  }
  if (t < 80) {   // qconst, K=128, 2 accumulators (gathers in flight above)
    float acc0 = ab1[t], acc1 = 0.f;
    const float* wq = wqcT + t * 132;
    for (int k = 0; k < 128; k += 8) {
      float4 w0 = *(const float4*)(wq + k);
      float4 w1 = *(const float4*)(wq + k + 4);
      float4 q0 = *(const float4*)(sQ + k);
      float4 q1 = *(const float4*)(sQ + k + 4);
      acc0 += q0.x * w0.x + q0.y * w0.y + q0.z * w0.z + q0.w * w0.w;
      acc1 += q1.x * w1.x + q1.y * w1.y + q1.z * w1.z + q1.w * w1.w;
    }
    sQCp[t] = acc0 + acc1;
  }
  short8 Bp[4];
  {
    const unsigned short* br = WsdpT + (size_t)(wv * 16 + m16) * 256 + quad * 8;
#pragma unroll
    for (int kt = 0; kt < 4; kt++) {
      short8 w1 = *(const short8*)(br + kt * 32);
      short8 w2 = *(const short8*)(br + 128 + kt * 32);
      int k0 = quad * 8 + kt * 32;
      Bp[kt] = fuseB(w1, w2, *(const float4*)(sQ + k0), *(const float4*)(sQ + k0 + 4));
    }
  }
  // land gathers into sX: l = i>>4, f = (i>>3)&1, 16B at (i&7)*8
  {
    int i0 = t, i1 = t + 256, i2 = t + 512;
    *(uint4*)(sX + (i0 >> 4) * XS + ((i0 >> 3) & 1) * 64 + (i0 & 7) * 8) = g0;
    *(uint4*)(sX + (i1 >> 4) * XS + ((i1 >> 3) & 1) * 64 + (i1 & 7) * 8) = g1;
    if (has3)
      *(uint4*)(sX + (i2 >> 4) * XS + ((i2 >> 3) & 1) * 64 + (i2 & 7) * 8) = g2;
  }
  if ((t & 15) == 0) {   // r = 2l units: i multiples of 16 (L1-hot seqi reload)
    int l = t >> 4;
    sMask[l]      = (seqi[b * 80 + (t >> 3)] != 0) ? 0.f : NEG_INF_F;
    sMask[16 + l] = (seqi[b * 80 + ((t + 256) >> 3)] != 0) ? 0.f : NEG_INF_F;
    if (t < 128)
      sMask[32 + l] = (seqi[b * 80 + ((t + 512) >> 3)] != 0) ? 0.f : NEG_INF_F;
  }
  __syncthreads();

  // ---- phase 3: layer1 MFMA, K=128, wave = N-tile; waves 0-2 inline nt=4 ----
  {
    const int h = wv * 16 + m16;
    const float qc = sQCp[h];
#pragma unroll
    for (int mt = 0; mt < 3; mt++) {
      f32x4 acc = {0.f, 0.f, 0.f, 0.f};
      const unsigned short* ar = sX + (mt * 16 + m16) * XS + quad * 8;
#pragma unroll
      for (int kt = 0; kt < 4; kt++) {
        short8 a = *(const short8*)(ar + kt * 32);
        acc = __builtin_amdgcn_mfma_f32_16x16x32_bf16(a, Bp[kt], acc, 0, 0, 0);
      }
      float s0 = sigm(acc[0] + qc), s1 = sigm(acc[1] + qc);
      float s2 = sigm(acc[2] + qc), s3 = sigm(acc[3] + qc);
      unsigned p01 = cvt_pk_bf16(s0, s1), p23 = cvt_pk_bf16(s2, s3);
      int l0 = mt * 16 + quad * 4;
      if (l0 < 40) {
        sH1[(l0 + 0) * HS + h] = (unsigned short)p01;
        sH1[(l0 + 1) * HS + h] = (unsigned short)(p01 >> 16);
        sH1[(l0 + 2) * HS + h] = (unsigned short)p23;
        sH1[(l0 + 3) * HS + h] = (unsigned short)(p23 >> 16);
      }
    }
    if (wv < 3) {   // nt = 4, mt = wv : load+fuse+mfma inline, no persistent frags
      const unsigned short* br = WsdpT + (size_t)(64 + m16) * 256 + quad * 8;
      const unsigned short* ar = sX + (wv * 16 + m16) * XS + quad * 8;
      f32x4 acc = {0.f, 0.f, 0.f, 0.f};
#pragma unroll
      for (int kt = 0; kt < 4; kt++) {
        short8 w1 = *(const short8*)(br + kt * 32);
        short8 w2 = *(const short8*)(br + 128 + kt * 32);
        int k0 = quad * 8 + kt * 32;
        short8 bp = fuseB(w1, w2, *(const float4*)(sQ + k0), *(const float4*)(sQ + k0 + 4));
        short8 a = *(const short8*)(ar + kt * 32);
        acc = __builtin_amdgcn_mfma_f32_16x16x32_bf16(a, bp, acc, 0, 0, 0);
      }
      int h4 = 64 + m16;
      float qc4 = sQCp[h4];
      float s0 = sigm(acc[0] + qc4), s1 = sigm(acc[1] + qc4);
      float s2 = sigm(acc[2] + qc4), s3 = sigm(acc[3] + qc4);
      unsigned p01 = cvt_pk_bf16(s0, s1), p23 = cvt_pk_bf16(s2, s3);
      int l0 = wv * 16 + quad * 4;
      if (l0 < 40) {
        sH1[(l0 + 0) * HS + h4] = (unsigned short)p01;
        sH1[(l0 + 1) * HS + h4] = (unsigned short)(p01 >> 16);
        sH1[(l0 + 2) * HS + h4] = (unsigned short)p23;
        sH1[(l0 + 3) * HS + h4] = (unsigned short)(p23 >> 16);
      }
    }
  }
  __syncthreads();

  // ---- phase 4: layer2 MFMA + fused logit reduction into sLA ----
  for (int tile = wv; tile < 9; tile += 4) {
    int mt = tile / 3, nt = tile % 3;
    f32x4 acc = {0.f, 0.f, 0.f, 0.f};
    int arow = mt * 16 + m16;
    if (arow > 39) arow = 39;   // keep garbage A-rows inside the LDS block (gated below)
    const unsigned short* ar = sH1 + arow * HS + quad * 8;
    const unsigned short* br = W2bT + (nt * 16 + m16) * 96 + quad * 8;
#pragma unroll
    for (int kt = 0; kt < 3; kt++) {
      short8 a = *(const short8*)(ar + kt * 32);
      short8 bb = *(const short8*)(br + kt * 32);
      acc = __builtin_amdgcn_mfma_f32_16x16x32_bf16(a, bb, acc, 0, 0, 0);
    }
    int j = nt * 16 + m16;
    float b2 = (j < 40) ? ab2[j] : 0.f;
    float wf = (j < 40) ? aWf[j] : 0.f;
    float c[4];
#pragma unroll
    for (int r = 0; r < 4; r++) {
      float h2 = sigm(acc[r] + b2);
      c[r] = (j < 40) ? h2 * wf : 0.f;    // gate garbage j-lanes (NaN-safe select)
    }
#pragma unroll
    for (int off = 1; off < 16; off <<= 1) {
#pragma unroll
      for (int r = 0; r < 4; r++) c[r] += __shfl_xor(c[r], off, 64);
    }
    if (m16 == 0) {
#pragma unroll
      for (int r = 0; r < 4; r++) {
        int l = mt * 16 + quad * 4 + r;
        if (l < 40) atomicAdd(&sLA[l], c[r]);
      }
    }
  }
  __syncthreads();

  // ---- phase 5+6: per-wave softmax + pool (waves 0,1; wave-local, no barrier) ----
  if (wv < 2) {
    float logit = -3.0e38f;
    if (ln < 40) logit = sLA[ln] + abf[0] + sMask[ln];
    float mx = logit;
    for (int off = 32; off; off >>= 1) mx = fmaxf(mx, __shfl_xor(mx, off, 64));
    float ex = (ln < 40) ? __expf(logit - mx) : 0.f;
    float sm = ex;
    for (int off = 32; off; off >>= 1) sm += __shfl_xor(sm, off, 64);
    float* av = sQCp + wv * 40;          // qconst space is dead now; per-wave att copy
    if (ln < 40) av[ln] = ex * __builtin_amdgcn_rcpf(sm);
    float acc = 0.f;
    for (int l = 0; l < 40; l++) acc += av[l] * bf2f(sX[l * XS + t]);
    xrow[t] = f2bf(acc);                 // pool cols 0..127
  }
  // waves 2,3 retire here
}

// ---------------- kernel B: batched FFN GEMM, 16 rows per block ----------------

__launch_bounds__(256, 2)
__global__ void din_ffn(const unsigned short* __restrict__ Xg,
                        const unsigned short* __restrict__ W1fT, const float* __restrict__ b1p,
                        const float* __restrict__ fa1,
                        const unsigned short* __restrict__ W2fT, const float* __restrict__ fb2,
                        const float* __restrict__ fa2,
                        const float* __restrict__ oW, const float* __restrict__ ob,
                        float* __restrict__ out) {
  __shared__ __align__(16) unsigned short sXB[16 * 488];
  __shared__ __align__(16) unsigned short sH1B[16 * HS];
  __shared__ float sH2B[16 * 41];
  const int t = threadIdx.x, blk = blockIdx.x;
  const int wv = t >> 6, ln = t & 63, m16 = ln & 15, quad = ln >> 4;

  // prefetch GEMM1 B-fragments for nt = wv (15 frags, K=480)
  short8 Bf[15];
  {
    const unsigned short* br = W1fT + (size_t)(wv * 16 + m16) * 480 + quad * 8;
#pragma unroll
    for (int kt = 0; kt < 15; kt++) Bf[kt] = *(const short8*)(br + kt * 32);
  }

  // stage X tile (16 rows x 480 bf16) + zero H1 K-pad
  for (int i = t; i < 960; i += 256) {
    int r = i / 60, c = i % 60;
    *(uint4*)(sXB + r * 488 + c * 8) =
        *(const uint4*)(Xg + (size_t)(blk * 16 + r) * XGS + c * 8);
  }
  if (t < 128) {
    int r = t >> 3, c = t & 7;
    ((unsigned*)sH1B)[r * 52 + 40 + c] = 0u;
  }
  __syncthreads();

  // GEMM1: [16x480] @ [480x80]; wave = N-tile; wave 0 also does nt=4
  {
    int h = wv * 16 + m16;
    f32x4 acc = {0.f, 0.f, 0.f, 0.f};
    const unsigned short* ar = sXB + m16 * 488 + quad * 8;
#pragma unroll
    for (int kt = 0; kt < 15; kt++) {
      short8 a = *(const short8*)(ar + kt * 32);
      acc = __builtin_amdgcn_mfma_f32_16x16x32_bf16(a, Bf[kt], acc, 0, 0, 0);
    }
    float b1v = b1p[h], a1v = fa1[h];
    float z0 = acc[0] + b1v, z1 = acc[1] + b1v, z2 = acc[2] + b1v, z3 = acc[3] + b1v;
    z0 = z0 > 0.f ? z0 : a1v * z0;
    z1 = z1 > 0.f ? z1 : a1v * z1;
    z2 = z2 > 0.f ? z2 : a1v * z2;
    z3 = z3 > 0.f ? z3 : a1v * z3;
    unsigned p01 = cvt_pk_bf16(z0, z1), p23 = cvt_pk_bf16(z2, z3);
    int l0 = quad * 4;
    sH1B[(l0 + 0) * HS + h] = (unsigned short)p01;
    sH1B[(l0 + 1) * HS + h] = (unsigned short)(p01 >> 16);
    sH1B[(l0 + 2) * HS + h] = (unsigned short)p23;
    sH1B[(l0 + 3) * HS + h] = (unsigned short)(p23 >> 16);
    if (wv == 0) {   // nt = 4
      short8 B4[15];
      const unsigned short* br = W1fT + (size_t)(64 + m16) * 480 + quad * 8;
#pragma unroll
      for (int kt = 0; kt < 15; kt++) B4[kt] = *(const short8*)(br + kt * 32);
      f32x4 acc4 = {0.f, 0.f, 0.f, 0.f};
#pragma unroll
      for (int kt = 0; kt < 15; kt++) {
        short8 a = *(const short8*)(ar + kt * 32);
        acc4 = __builtin_amdgcn_mfma_f32_16x16x32_bf16(a, B4[kt], acc4, 0, 0, 0);
      }
      int h4 = 64 + m16;
      float b1v4 = b1p[h4], a1v4 = fa1[h4];
      float y0 = acc4[0] + b1v4, y1 = acc4[1] + b1v4, y2 = acc4[2] + b1v4, y3 = acc4[3] + b1v4;
      y0 = y0 > 0.f ? y0 : a1v4 * y0;
      y1 = y1 > 0.f ? y1 : a1v4 * y1;
      y2 = y2 > 0.f ? y2 : a1v4 * y2;
      y3 = y3 > 0.f ? y3 : a1v4 * y3;
      unsigned q01 = cvt_pk_bf16(y0, y1), q23 = cvt_pk_bf16(y2, y3);
      sH1B[(l0 + 0) * HS + h4] = (unsigned short)q01;
      sH1B[(l0 + 1) * HS + h4] = (unsigned short)(q01 >> 16);
      sH1B[(l0 + 2) * HS + h4] = (unsigned short)q23;
      sH1B[(l0 + 3) * HS + h4] = (unsigned short)(q23 >> 16);
    }
  }
  __syncthreads();

  // GEMM2: [16x96] @ [96x48], waves 0-2
  if (wv < 3) {
    f32x4 acc = {0.f, 0.f, 0.f, 0.f};
    const unsigned short* ar = sH1B + m16 * HS + quad * 8;
    const unsigned short* br = W2fT + (wv * 16 + m16) * 96 + quad * 8;
#pragma unroll
    for (int kt = 0; kt < 3; kt++) {
      short8 a = *(const short8*)(ar + kt * 32);
      short8 bb = *(const short8*)(br + kt * 32);
      acc = __builtin_amdgcn_mfma_f32_16x16x32_bf16(a, bb, acc, 0, 0, 0);
    }
    int j = wv * 16 + m16;
    if (j < 40) {
      float b2 = fb2[j], a2 = fa2[j];
#pragma unroll
      for (int r = 0; r < 4; r++) {
        int l = quad * 4 + r;
        float z = acc[r] + b2;
        sH2B[l * 41 + j] = z > 0.f ? z : a2 * z;
      }
    }
  }
  __syncthreads();

  // final dot(40) + sigmoid
  if (t < 16) {
    float acc = ob[0];
    for (int j = 0; j < 40; j++) acc += sH2B[t * 41 + j] * oW[j];
    out[blk * 16 + t] = sigm(acc);
  }
}

// ---------------- launch ----------------

extern "C" void kernel_launch(void* const* d_in, const int* in_sizes, int n_in,
                              void* d_out, int out_size, void* d_ws, size_t ws_size,
                              hipStream_t stream) {
  const float* dense  = (const float*)d_in[0];
  const int*   sparsei = (const int*)d_in[1];
  const int*   seqi   = (const int*)d_in[2];
  const int*   itemi  = (const int*)d_in[3];
  const float* embS   = (const float*)d_in[4];
  const float* embQ   = (const float*)d_in[5];
  const float* aW1    = (const float*)d_in[6];
  const float* ab1    = (const float*)d_in[7];
  const float* aW2    = (const float*)d_in[8];
  const float* ab2    = (const float*)d_in[9];
  const float* aWf    = (const float*)d_in[10];
  const float* abf    = (const float*)d_in[11];
  const float* bng    = (const float*)d_in[12];
  const float* bnb    = (const float*)d_in[13];
  const float* bnm    = (const float*)d_in[14];
  const float* bnv    = (const float*)d_in[15];
  const float* fW1    = (const float*)d_in[16];
  const float* fb1    = (const float*)d_in[17];
  const float* fa1    = (const float*)d_in[18];
  const float* fW2    = (const float*)d_in[19];
  const float* fb2    = (const float*)d_in[20];
  const float* fa2    = (const float*)d_in[21];
  const float* oW     = (const float*)d_in[22];
  const float* ob     = (const float*)d_in[23];
  float* out = (float*)d_out;

  float* ws = (float*)d_ws;
  float* wqcT = ws;                                          // 10560 f
  float* b1p  = ws + 10560;                                  // 80 f
  unsigned short* WsdpT = (unsigned short*)(ws + 10640);     // 20480 u16
  unsigned short* W2bT  = (unsigned short*)(ws + 20880);     // 4608 u16
  unsigned short* W2fT  = (unsigned short*)(ws + 23184);     // 4608 u16
  unsigned short* W1fT  = (unsigned short*)(ws + 25488);     // 38400 u16
  unsigned short* Xg    = (unsigned short*)(ws + 44688);     // 8192*480 u16 = 7864320 B

  // bf16 copy of embQ (12.8M bf16 = 25.6 MB) after Xg, if workspace allows
  size_t base = 44688ull * 4 + 8192ull * 480 * 2;            // 8,043,072 B (16B aligned)
  size_t need = base + 12800000ull * 2;
  unsigned short* embQb = (ws_size >= need)
      ? (unsigned short*)((char*)d_ws + base) : (unsigned short*)0;

  int prep_grid = embQb ? 2354 : 306;
  prep_all<<<prep_grid, 256, 0, stream>>>(aW1, wqcT, WsdpT, aW2, W2bT, fW2, W2fT,
                                          fW1, bng, bnv, W1fT, fb1, bnb, bnm, b1p,
                                          embQ, embQb);
  din_att<<<BB, 256, 0, stream>>>(dense, sparsei, seqi, itemi, embS, embQ, embQb,
                                  wqcT, WsdpT, W2bT, ab1, ab2, aWf, abf, Xg);
  din_ffn<<<512, 256, 0, stream>>>(Xg, W1fT, b1p, fa1, W2fT, fb2, fa2, oW, ob, out);
}

// Round 7
// 316.479 us; speedup vs baseline: 1.0602x; 1.0403x over previous
//
#include <hip/hip_runtime.h>

#define BB 8192
#define LL 40
#define VV 100000
#define NEG_INF_F (-4294967295.0f)
#define XS 136    // sX row stride (bf16): 128 + 8 pad
#define HS 104    // sH1 row stride (bf16), K padded 80->96
#define XGS 480   // global info_all row stride (bf16), K padded 456->480

typedef __attribute__((ext_vector_type(8))) short short8;
typedef __attribute__((ext_vector_type(4))) float f32x4;

// gfx950 HW bf16 convert: 2 f32 -> packed 2x bf16 (RNE), 1 VALU op.
__device__ __forceinline__ unsigned cvt_pk_bf16(float a, float b) {
  unsigned r;
  asm("v_cvt_pk_bf16_f32 %0, %1, %2" : "=v"(r) : "v"(a), "v"(b));
  return r;
}
__device__ __forceinline__ unsigned short f2bf(float f) {
  return (unsigned short)cvt_pk_bf16(f, f);
}
__device__ __forceinline__ float bf2f(unsigned short s) {
  return __uint_as_float(((unsigned)s) << 16);
}
// sigmoid with v_rcp (1 ulp) instead of the ~10-op exact divide sequence
__device__ __forceinline__ float sigm(float z) {
  return __builtin_amdgcn_rcpf(1.f + __expf(-z));
}

// B' = bf16( Wsd + q * Wd )
__device__ __forceinline__ short8 fuseB(short8 wsd, short8 wd, float4 qa, float4 qb) {
  float qv[8] = {qa.x, qa.y, qa.z, qa.w, qb.x, qb.y, qb.z, qb.w};
  float f[8];
#pragma unroll
  for (int j = 0; j < 8; j++)
    f[j] = bf2f((unsigned short)wsd[j]) + qv[j] * bf2f((unsigned short)wd[j]);
  uint4 o;
  o.x = cvt_pk_bf16(f[0], f[1]);
  o.y = cvt_pk_bf16(f[2], f[3]);
  o.z = cvt_pk_bf16(f[4], f[5]);
  o.w = cvt_pk_bf16(f[6], f[7]);
  return __builtin_bit_cast(short8, o);
}

// ---------------- prep (fused, parallel) ----------------
__global__ void prep_all(const float* __restrict__ W1, float* __restrict__ wqcT,
                         unsigned short* __restrict__ WsdpT,
                         const float* __restrict__ aW2, unsigned short* __restrict__ W2bT,
                         const float* __restrict__ fW2, unsigned short* __restrict__ W2fT,
                         const float* __restrict__ fW1, const float* __restrict__ g,
                         const float* __restrict__ vr, unsigned short* __restrict__ W1fT,
                         const float* __restrict__ fb1, const float* __restrict__ be,
                         const float* __restrict__ mn, float* __restrict__ b1p) {
  __shared__ float red[4];
  int bid = blockIdx.x, t = threadIdx.x;
  if (bid < 40) {
    int i = bid * 256 + t;           // exactly 10240
    int h = i >> 7, k = i & 127;
    float a = W1[k * 80 + h];
    float b = W1[(128 + k) * 80 + h];
    float c = W1[(256 + k) * 80 + h];
    float d = W1[(384 + k) * 80 + h];
    wqcT[h * 132 + k] = a + c;
    WsdpT[h * 256 + k] = f2bf(b - c);
    WsdpT[h * 256 + 128 + k] = f2bf(d);
  } else if (bid < 58) {
    int i = (bid - 40) * 256 + t;    // exactly 4608
    int n = i / 96, k = i % 96;
    W2bT[i] = (n < 40 && k < 80) ? f2bf(aW2[k * 40 + n]) : (unsigned short)0;
  } else if (bid < 76) {
    int i = (bid - 58) * 256 + t;
    int n = i / 96, k = i % 96;
    W2fT[i] = (n < 40 && k < 80) ? f2bf(fW2[k * 40 + n]) : (unsigned short)0;
  } else if (bid < 226) {
    int i = (bid - 76) * 256 + t;    // exactly 38400
    int n = i / 480, k = i % 480;
    float v = 0.f;
    if (k < 456) v = fW1[k * 80 + n] * g[k] * rsqrtf(vr[k] + 1e-3f);
    W1fT[i] = f2bf(v);
  } else {
    int n = bid - 226;               // 0..79
    float p = 0.f;
    for (int k = t; k < 456; k += 256) {
      float sc = g[k] * rsqrtf(vr[k] + 1e-3f);
      p += (be[k] - mn[k] * sc) * fW1[k * 80 + n];
    }
    for (int off = 32; off; off >>= 1) p += __shfl_xor(p, off, 64);
    if ((t & 63) == 0) red[t >> 6] = p;
    __syncthreads();
    if (t == 0) b1p[n] = fb1[n] + red[0] + red[1] + red[2] + red[3];
  }
}

// ---------------- kernel A: attention + pool, one row per block ----------------
// Round-1 verified body, verbatim (155.5 us, absmax 0.0039). Gathers issue into
// regs, q-compute overlaps their latency; per-wave softmax (waves 0,1).

__launch_bounds__(256, 8)
__global__ void din_att(const float* __restrict__ dense, const int* __restrict__ sparsei,
                        const int* __restrict__ seqi, const int* __restrict__ itemi,
                        const float* __restrict__ embS, const float* __restrict__ embQ,
                        const float* __restrict__ wqcT, const unsigned short* __restrict__ WsdpT,
                        const unsigned short* __restrict__ W2bT,
                        const float* __restrict__ ab1, const float* __restrict__ ab2,
                        const float* __restrict__ aWf, const float* __restrict__ abf,
                        unsigned short* __restrict__ Xg) {
  __shared__ __align__(16) char smem[20352];
  unsigned short* sX  = (unsigned short*)smem;             // 40 x 136 bf16
  unsigned short* sH1 = (unsigned short*)(smem + 10880);   // 40 x 104 bf16
  float* sQ    = (float*)(smem + 19200);                   // 128
  float* sQCp  = sQ + 128;                                 // 80 (qconst; later 2x40 att)
  float* sLA   = sQCp + 80;                                // 40 (logit accum)
  float* sMask = sLA + 40;                                 // 40

  const int t = threadIdx.x;        // 0..255
  const int b = blockIdx.x;
  const int wv = t >> 6, ln = t & 63, m16 = ln & 15, quad = ln >> 4;
  unsigned short* xrow = Xg + (size_t)b * XGS;

  // ---- phase 0: item gather -> sQ (+ Xg item cols) + zero inits ----
  if (t < 32) {
    int f = t >> 4, sub = t & 15;
    int idx = itemi[b * 2 + f];
    float4 v = *(const float4*)(embQ + ((size_t)(f * VV + idx)) * 64 + sub * 4);
    *(float4*)(sQ + f * 64 + sub * 4) = v;
    uint2 p;
    p.x = cvt_pk_bf16(v.x, v.y);
    p.y = cvt_pk_bf16(v.z, v.w);
    *(uint2*)(xrow + 128 + f * 64 + sub * 4) = p;          // item cols 128..255
  } else if (t >= 100 && t < 140) {
    sLA[t - 100] = 0.f;
  }
  for (int i = t; i < 320; i += 256) {   // sH1 K-pad cols 80..95, rows 0..39 (NaN guard)
    int r = i >> 3, c = i & 7;
    ((unsigned*)sH1)[r * 52 + 40 + c] = 0u;
  }
  __syncthreads();

  // ---- phase 2: issue seq gathers -> regs; overlap sparse/dense Xg, qconst, B' ----
  uint2 gv[5];
#pragma unroll
  for (int it = 0; it < 5; it++) {
    int i = t + (it << 8);
    int r = i >> 4, sub = i & 15, f = r & 1;
    int idx = seqi[b * 80 + r];
    float4 v = *(const float4*)(embQ + ((size_t)(f * VV + idx)) * 64 + sub * 4);
    gv[it].x = cvt_pk_bf16(v.x, v.y);
    gv[it].y = cvt_pk_bf16(v.z, v.w);
  }
  if (t >= 32 && t < 80) {
    int j = t - 32, f = j >> 4, sub = j & 15;
    int idx = sparsei[b * 3 + f];
    float4 v = *(const float4*)(embS + ((size_t)(f * VV + idx)) * 64 + sub * 4);
    uint2 p;
    p.x = cvt_pk_bf16(v.x, v.y);
    p.y = cvt_pk_bf16(v.z, v.w);
    *(uint2*)(xrow + 264 + f * 64 + sub * 4) = p;          // sparse cols 264..455
  } else if (t >= 80 && t < 88) {
    xrow[256 + (t - 80)] = f2bf(dense[b * 8 + (t - 80)]);  // dense cols 256..263
  } else if (t >= 88 && t < 100) {
    ((unsigned*)xrow)[228 + (t - 88)] = 0u;                // K-pad cols 456..479
  }
  if (t < 80) {   // qconst, K=128, 2 accumulators (gathers in flight above)
    float acc0 = ab1[t], acc1 = 0.f;
    const float* wq = wqcT + t * 132;
    for (int k = 0; k < 128; k += 8) {
      float4 w0 = *(const float4*)(wq + k);
      float4 w1 = *(const float4*)(wq + k + 4);
      float4 q0 = *(const float4*)(sQ + k);
      float4 q1 = *(const float4*)(sQ + k + 4);
      acc0 += q0.x * w0.x + q0.y * w0.y + q0.z * w0.z + q0.w * w0.w;
      acc1 += q1.x * w1.x + q1.y * w1.y + q1.z * w1.z + q1.w * w1.w;
    }
    sQCp[t] = acc0 + acc1;
  }
  short8 Bp[4];
  {
    const unsigned short* br = WsdpT + (size_t)(wv * 16 + m16) * 256 + quad * 8;
#pragma unroll
    for (int kt = 0; kt < 4; kt++) {
      short8 w1 = *(const short8*)(br + kt * 32);
      short8 w2 = *(const short8*)(br + 128 + kt * 32);
      int k0 = quad * 8 + kt * 32;
      Bp[kt] = fuseB(w1, w2, *(const float4*)(sQ + k0), *(const float4*)(sQ + k0 + 4));
    }
  }
  // land gathers into sX + mask
#pragma unroll
  for (int it = 0; it < 5; it++) {
    int i = t + (it << 8);
    int r = i >> 4, sub = i & 15, l = r >> 1, f = r & 1;
    *(uint2*)(sX + l * XS + f * 64 + sub * 4) = gv[it];
  }
  if ((t & 31) == 0) {   // threads 0,32,..: r even & sub==0 for all 5 its (L1-hot reload)
#pragma unroll
    for (int it = 0; it < 5; it++) {
      int r = (t >> 4) + (it << 4);
      sMask[r >> 1] = (seqi[b * 80 + r] != 0) ? 0.f : NEG_INF_F;
    }
  }
  __syncthreads();

  // ---- phase 3: layer1 MFMA, K=128, wave = N-tile; waves 0-2 inline nt=4 ----
  {
    const int h = wv * 16 + m16;
    const float qc = sQCp[h];
#pragma unroll
    for (int mt = 0; mt < 3; mt++) {
      f32x4 acc = {0.f, 0.f, 0.f, 0.f};
      const unsigned short* ar = sX + (mt * 16 + m16) * XS + quad * 8;
#pragma unroll
      for (int kt = 0; kt < 4; kt++) {
        short8 a = *(const short8*)(ar + kt * 32);
        acc = __builtin_amdgcn_mfma_f32_16x16x32_bf16(a, Bp[kt], acc, 0, 0, 0);
      }
      float s0 = sigm(acc[0] + qc), s1 = sigm(acc[1] + qc);
      float s2 = sigm(acc[2] + qc), s3 = sigm(acc[3] + qc);
      unsigned p01 = cvt_pk_bf16(s0, s1), p23 = cvt_pk_bf16(s2, s3);
      int l0 = mt * 16 + quad * 4;           // either all 4 rows valid or none
      if (l0 < 40) {
        sH1[(l0 + 0) * HS + h] = (unsigned short)p01;
        sH1[(l0 + 1) * HS + h] = (unsigned short)(p01 >> 16);
        sH1[(l0 + 2) * HS + h] = (unsigned short)p23;
        sH1[(l0 + 3) * HS + h] = (unsigned short)(p23 >> 16);
      }
    }
    if (wv < 3) {   // nt = 4, mt = wv : load+fuse+mfma inline, no persistent frags
      const unsigned short* br = WsdpT + (size_t)(64 + m16) * 256 + quad * 8;
      const unsigned short* ar = sX + (wv * 16 + m16) * XS + quad * 8;
      f32x4 acc = {0.f, 0.f, 0.f, 0.f};
#pragma unroll
      for (int kt = 0; kt < 4; kt++) {
        short8 w1 = *(const short8*)(br + kt * 32);
        short8 w2 = *(const short8*)(br + 128 + kt * 32);
        int k0 = quad * 8 + kt * 32;
        short8 bp = fuseB(w1, w2, *(const float4*)(sQ + k0), *(const float4*)(sQ + k0 + 4));
        short8 a = *(const short8*)(ar + kt * 32);
        acc = __builtin_amdgcn_mfma_f32_16x16x32_bf16(a, bp, acc, 0, 0, 0);
      }
      int h4 = 64 + m16;
      float qc4 = sQCp[h4];
      float s0 = sigm(acc[0] + qc4), s1 = sigm(acc[1] + qc4);
      float s2 = sigm(acc[2] + qc4), s3 = sigm(acc[3] + qc4);
      unsigned p01 = cvt_pk_bf16(s0, s1), p23 = cvt_pk_bf16(s2, s3);
      int l0 = wv * 16 + quad * 4;
      if (l0 < 40) {
        sH1[(l0 + 0) * HS + h4] = (unsigned short)p01;
        sH1[(l0 + 1) * HS + h4] = (unsigned short)(p01 >> 16);
        sH1[(l0 + 2) * HS + h4] = (unsigned short)p23;
        sH1[(l0 + 3) * HS + h4] = (unsigned short)(p23 >> 16);
      }
    }
  }
  __syncthreads();

  // ---- phase 4: layer2 MFMA + fused logit reduction into sLA ----
  for (int tile = wv; tile < 9; tile += 4) {
    int mt = tile / 3, nt = tile % 3;
    f32x4 acc = {0.f, 0.f, 0.f, 0.f};
    int arow = mt * 16 + m16;
    if (arow > 39) arow = 39;   // keep garbage A-rows inside the LDS block (gated below)
    const unsigned short* ar = sH1 + arow * HS + quad * 8;
    const unsigned short* br = W2bT + (nt * 16 + m16) * 96 + quad * 8;
#pragma unroll
    for (int kt = 0; kt < 3; kt++) {
      short8 a = *(const short8*)(ar + kt * 32);
      short8 bb = *(const short8*)(br + kt * 32);
      acc = __builtin_amdgcn_mfma_f32_16x16x32_bf16(a, bb, acc, 0, 0, 0);
    }
    int j = nt * 16 + m16;
    float b2 = (j < 40) ? ab2[j] : 0.f;
    float wf = (j < 40) ? aWf[j] : 0.f;
    float c[4];
#pragma unroll
    for (int r = 0; r < 4; r++) {
      float h2 = sigm(acc[r] + b2);
      c[r] = (j < 40) ? h2 * wf : 0.f;    // gate garbage j-lanes (NaN-safe select)
    }
#pragma unroll
    for (int off = 1; off < 16; off <<= 1) {
#pragma unroll
      for (int r = 0; r < 4; r++) c[r] += __shfl_xor(c[r], off, 64);
    }
    if (m16 == 0) {
#pragma unroll
      for (int r = 0; r < 4; r++) {
        int l = mt * 16 + quad * 4 + r;
        if (l < 40) atomicAdd(&sLA[l], c[r]);
      }
    }
  }
  __syncthreads();

  // ---- phase 5+6: per-wave softmax + pool (waves 0,1; wave-local, no barrier) ----
  if (wv < 2) {
    float logit = -3.0e38f;
    if (ln < 40) logit = sLA[ln] + abf[0] + sMask[ln];
    float mx = logit;
    for (int off = 32; off; off >>= 1) mx = fmaxf(mx, __shfl_xor(mx, off, 64));
    float ex = (ln < 40) ? __expf(logit - mx) : 0.f;
    float sm = ex;
    for (int off = 32; off; off >>= 1) sm += __shfl_xor(sm, off, 64);
    float* av = sQCp + wv * 40;          // qconst space is dead now; per-wave att copy
    if (ln < 40) av[ln] = ex * __builtin_amdgcn_rcpf(sm);
    float acc = 0.f;
    for (int l = 0; l < 40; l++) acc += av[l] * bf2f(sX[l * XS + t]);
    xrow[t] = f2bf(acc);                 // pool cols 0..127
  }
  // waves 2,3 retire here
}

// ---------------- kernel B: batched FFN GEMM, 16 rows per block ----------------
// NEW this round: 320 threads = 5 symmetric waves, wave w owns N-tile w exactly
// (the old wave-0 B4 double-duty path, with its 30 live B-fragments, is gone).
// Same LDS, same per-tile indexing (wave 4 uses the same (64+m16)*480 addressing
// the old B4 path used). Probes whether din_ffn is the hidden ~140 us.

__launch_bounds__(320, 2)
__global__ void din_ffn(const unsigned short* __restrict__ Xg,
                        const unsigned short* __restrict__ W1fT, const float* __restrict__ b1p,
                        const float* __restrict__ fa1,
                        const unsigned short* __restrict__ W2fT, const float* __restrict__ fb2,
                        const float* __restrict__ fa2,
                        const float* __restrict__ oW, const float* __restrict__ ob,
                        float* __restrict__ out) {
  __shared__ __align__(16) unsigned short sXB[16 * 488];
  __shared__ __align__(16) unsigned short sH1B[16 * HS];
  __shared__ float sH2B[16 * 41];
  const int t = threadIdx.x, blk = blockIdx.x;   // t: 0..319
  const int wv = t >> 6, ln = t & 63, m16 = ln & 15, quad = ln >> 4;

  // prefetch GEMM1 B-fragments for nt = wv (15 frags, K=480); wv 0..4 covers h 0..79
  short8 Bf[15];
  {
    const unsigned short* br = W1fT + (size_t)(wv * 16 + m16) * 480 + quad * 8;
#pragma unroll
    for (int kt = 0; kt < 15; kt++) Bf[kt] = *(const short8*)(br + kt * 32);
  }

  // stage X tile (16 rows x 480 bf16) + zero H1 K-pad
  for (int i = t; i < 960; i += 320) {
    int r = i / 60, c = i % 60;
    *(uint4*)(sXB + r * 488 + c * 8) =
        *(const uint4*)(Xg + (size_t)(blk * 16 + r) * XGS + c * 8);
  }
  if (t < 128) {
    int r = t >> 3, c = t & 7;
    ((unsigned*)sH1B)[r * 52 + 40 + c] = 0u;
  }
  __syncthreads();

  // GEMM1: [16x480] @ [480x80]; wave = N-tile, all 5 waves symmetric
  {
    int h = wv * 16 + m16;
    f32x4 acc = {0.f, 0.f, 0.f, 0.f};
    const unsigned short* ar = sXB + m16 * 488 + quad * 8;
#pragma unroll
    for (int kt = 0; kt < 15; kt++) {
      short8 a = *(const short8*)(ar + kt * 32);
      acc = __builtin_amdgcn_mfma_f32_16x16x32_bf16(a, Bf[kt], acc, 0, 0, 0);
    }
    float b1v = b1p[h], a1v = fa1[h];
    float z0 = acc[0] + b1v, z1 = acc[1] + b1v, z2 = acc[2] + b1v, z3 = acc[3] + b1v;
    z0 = z0 > 0.f ? z0 : a1v * z0;
    z1 = z1 > 0.f ? z1 : a1v * z1;
    z2 = z2 > 0.f ? z2 : a1v * z2;
    z3 = z3 > 0.f ? z3 : a1v * z3;
    unsigned p01 = cvt_pk_bf16(z0, z1), p23 = cvt_pk_bf16(z2, z3);
    int l0 = quad * 4;
    sH1B[(l0 + 0) * HS + h] = (unsigned short)p01;
    sH1B[(l0 + 1) * HS + h] = (unsigned short)(p01 >> 16);
    sH1B[(l0 + 2) * HS + h] = (unsigned short)p23;
    sH1B[(l0 + 3) * HS + h] = (unsigned short)(p23 >> 16);
  }
  __syncthreads();

  // GEMM2: [16x96] @ [96x48], waves 0-2
  if (wv < 3) {
    f32x4 acc = {0.f, 0.f, 0.f, 0.f};
    const unsigned short* ar = sH1B + m16 * HS + quad * 8;
    const unsigned short* br = W2fT + (wv * 16 + m16) * 96 + quad * 8;
#pragma unroll
    for (int kt = 0; kt < 3; kt++) {
      short8 a = *(const short8*)(ar + kt * 32);
      short8 bb = *(const short8*)(br + kt * 32);
      acc = __builtin_amdgcn_mfma_f32_16x16x32_bf16(a, bb, acc, 0, 0, 0);
    }
    int j = wv * 16 + m16;
    if (j < 40) {
      float b2 = fb2[j], a2 = fa2[j];
#pragma unroll
      for (int r = 0; r < 4; r++) {
        int l = quad * 4 + r;
        float z = acc[r] + b2;
        sH2B[l * 41 + j] = z > 0.f ? z : a2 * z;
      }
    }
  }
  __syncthreads();

  // final dot(40) + sigmoid
  if (t < 16) {
    float acc = ob[0];
    for (int j = 0; j < 40; j++) acc += sH2B[t * 41 + j] * oW[j];
    out[blk * 16 + t] = sigm(acc);
  }
}

// ---------------- launch ----------------

extern "C" void kernel_launch(void* const* d_in, const int* in_sizes, int n_in,
                              void* d_out, int out_size, void* d_ws, size_t ws_size,
                              hipStream_t stream) {
  const float* dense  = (const float*)d_in[0];
  const int*   sparsei = (const int*)d_in[1];
  const int*   seqi   = (const int*)d_in[2];
  const int*   itemi  = (const int*)d_in[3];
  const float* embS   = (const float*)d_in[4];
  const float* embQ   = (const float*)d_in[5];
  const float* aW1    = (const float*)d_in[6];
  const float* ab1    = (const float*)d_in[7];
  const float* aW2    = (const float*)d_in[8];
  const float* ab2    = (const float*)d_in[9];
  const float* aWf    = (const float*)d_in[10];
  const float* abf    = (const float*)d_in[11];
  const float* bng    = (const float*)d_in[12];
  const float* bnb    = (const float*)d_in[13];
  const float* bnm    = (const float*)d_in[14];
  const float* bnv    = (const float*)d_in[15];
  const float* fW1    = (const float*)d_in[16];
  const float* fb1    = (const float*)d_in[17];
  const float* fa1    = (const float*)d_in[18];
  const float* fW2    = (const float*)d_in[19];
  const float* fb2    = (const float*)d_in[20];
  const float* fa2    = (const float*)d_in[21];
  const float* oW     = (const float*)d_in[22];
  const float* ob     = (const float*)d_in[23];
  float* out = (float*)d_out;

  float* ws = (float*)d_ws;
  float* wqcT = ws;                                          // 10560 f
  float* b1p  = ws + 10560;                                  // 80 f
  unsigned short* WsdpT = (unsigned short*)(ws + 10640);     // 20480 u16
  unsigned short* W2bT  = (unsigned short*)(ws + 20880);     // 4608 u16
  unsigned short* W2fT  = (unsigned short*)(ws + 23184);     // 4608 u16
  unsigned short* W1fT  = (unsigned short*)(ws + 25488);     // 38400 u16
  unsigned short* Xg    = (unsigned short*)(ws + 44688);     // 8192*480 u16

  prep_all<<<306, 256, 0, stream>>>(aW1, wqcT, WsdpT, aW2, W2bT, fW2, W2fT,
                                    fW1, bng, bnv, W1fT, fb1, bnb, bnm, b1p);
  din_att<<<BB, 256, 0, stream>>>(dense, sparsei, seqi, itemi, embS, embQ,
                                  wqcT, WsdpT, W2bT, ab1, ab2, aWf, abf, Xg);
  din_ffn<<<512, 320, 0, stream>>>(Xg, W1fT, b1p, fa1, W2fT, fb2, fa2, oW, ob, out);
}